// Round 7
// baseline (597.881 us; speedup 1.0000x reference)
//
#include <hip/hip_runtime.h>
#include <hip/hip_bf16.h>

#define NLAYERS 3
#define BB 32
#define LL 336
#define LP 352                 // K-padded stride for Tb16 / W1t (zeros in pad)
#define NN 321
#define EE 4
#define DHID 512
#define PP 96
#define STOT (BB*NN*LL)        // 3451392
#define MROWS (BB*NN)          // 10272
#define BPN ((size_t)BB*PP*NN) // 986112

typedef __attribute__((ext_vector_type(8))) short short8;
typedef __attribute__((ext_vector_type(4))) float float4v;

union BF { __hip_bfloat16 h; short s; };

__device__ __forceinline__ short f2b(float f) { BF u; u.h = __float2bfloat16(f); return u.s; }

__device__ __forceinline__ float fast_tanh(float y) {
    float e = __expf(2.0f * y);
    return 1.0f - 2.0f / (e + 1.0f);   // exact limits at +-inf
}
__device__ __forceinline__ float gelu_f(float x) {
    return 0.5f * x * (1.0f + fast_tanh(0.7978845608028654f * (x + 0.044715f * x * x * x)));
}
__device__ __forceinline__ float softplus_f(float x) {
    return fmaxf(x, 0.0f) + log1pf(expf(-fabsf(x)));
}

// ---------------- RevIN stats: mu/inv per (b,n); also zeros loss ----------------
__global__ __launch_bounds__(256) void revin_stats(
    const float* __restrict__ x, float* __restrict__ MU, float* __restrict__ IV,
    float* __restrict__ loss)
{
    int b = blockIdx.x, nt = blockIdx.y;
    int tid = threadIdx.x;
    if (b == 0 && nt == 0 && tid == 0) loss[0] = 0.0f;
    int ni = tid & 63, lc = tid >> 6;
    int n = nt * 64 + ni;
    float s = 0.f, ss = 0.f;
    if (n < NN) {
        const float* xp = x + ((size_t)b * LL + lc * 84) * NN + n;
        for (int l = 0; l < 84; ++l, xp += NN) {
            float v = *xp; s += v; ss = fmaf(v, v, ss);
        }
    }
    __shared__ float Ss[4][64], Sq[4][64];
    Ss[lc][ni] = s; Sq[lc][ni] = ss;
    __syncthreads();
    if (lc == 0 && n < NN) {
        float st = ((Ss[0][ni] + Ss[1][ni]) + Ss[2][ni]) + Ss[3][ni];
        float sq = ((Sq[0][ni] + Sq[1][ni]) + Sq[2][ni]) + Sq[3][ni];
        float mu  = st * (1.0f / LL);
        float var = sq * (1.0f / LL) - mu * mu;   // ddof=0
        float inv = 1.0f / sqrtf(var + 1e-5f);
        MU[b * NN + n] = mu;
        IV[b * NN + n] = inv;
    }
}

// ---------------- RevIN transpose+normalize: T (stride LL) + Tb16 (stride LP) ----------------
__global__ __launch_bounds__(256) void revin_tn(
    const float* __restrict__ x, const float* __restrict__ MU, const float* __restrict__ IV,
    float* __restrict__ T, short* __restrict__ Tb16)
{
    int b = blockIdx.x, nt = blockIdx.y, lt = blockIdx.z;
    int n0 = nt * 64, l0 = lt * 48;
    __shared__ float Ls[48][65];
    int tid = threadIdx.x;
    #pragma unroll
    for (int i = 0; i < 12; ++i) {
        int lin = tid + i * 256;
        int li = lin >> 6, ni = lin & 63;
        int n = n0 + ni;
        Ls[li][ni] = (n < NN) ? x[((size_t)b * LL + l0 + li) * NN + n] : 0.f;
    }
    __syncthreads();
    int r = tid >> 2, q = tid & 3;
    int n = n0 + r;
    if (n >= NN) return;
    float mu = MU[b * NN + n], iv = IV[b * NN + n];
    size_t rowf = (size_t)(b * NN + n) * LL + l0;
    size_t rowb = (size_t)(b * NN + n) * LP + l0;
    #pragma unroll
    for (int k = 0; k < 3; ++k) {
        int c = (q + 4 * k) * 4;
        float4 v;
        v.x = (Ls[c    ][r] - mu) * iv;
        v.y = (Ls[c + 1][r] - mu) * iv;
        v.z = (Ls[c + 2][r] - mu) * iv;
        v.w = (Ls[c + 3][r] - mu) * iv;
        *(float4*)&T[rowf + c] = v;
        union { short s[4]; uint2 u; } pk;
        pk.s[0] = f2b(v.x); pk.s[1] = f2b(v.y); pk.s[2] = f2b(v.z); pk.s[3] = f2b(v.w);
        *(uint2*)&Tb16[rowb + c] = pk.u;
    }
    if (lt == 6 && q == 3) {   // zero the K-pad cols 336..352 (re-poisoned every call)
        size_t base = (size_t)(b * NN + n) * LP;
        *(uint4*)&Tb16[base + 336] = make_uint4(0, 0, 0, 0);
        *(uint4*)&Tb16[base + 344] = make_uint4(0, 0, 0, 0);
    }
}

// ---------------- tiled transpose+convert: dst[d][k(KS-strided)] <- bf16(src[k][d]) ----------------
__global__ __launch_bounds__(256) void wtrans_kernel(
    const float* __restrict__ src0, short* __restrict__ dst0, int K, int D, int KS)
{
    int le = blockIdx.z;
    const float* src = src0 + (size_t)le * K * D;
    short* dst = dst0 + (size_t)le * D * KS;
    int d0 = blockIdx.x * 64, k0 = blockIdx.y * 64;
    __shared__ short Ws[64][72];
    int tid = threadIdx.x;
    #pragma unroll
    for (int i = 0; i < 16; ++i) {
        int lin = tid + i * 256;
        int ki = lin >> 6, dj = lin & 63;
        int k = k0 + ki, d = d0 + dj;
        Ws[ki][dj] = (k < K && d < D) ? f2b(src[(size_t)k * D + d]) : (short)0;
    }
    __syncthreads();
    int di = tid >> 2, d = d0 + di;
    if (d >= D) return;
    #pragma unroll
    for (int kp = 0; kp < 2; ++kp) {
        int kj = ((tid & 3) + 4 * kp) * 8;
        if (k0 + kj >= KS) continue;
        union { short s[8]; uint4 u; } pk;
        #pragma unroll
        for (int j = 0; j < 8; ++j) pk.s[j] = Ws[kj + j][di];
        *(uint4*)(dst + (size_t)d * KS + k0 + kj) = pk.u;
    }
}

// ---------------- small convert for p1w/p2w (already [n][k]) ----------------
__global__ __launch_bounds__(256) void pcvt_kernel(
    const float* __restrict__ p1w, const float* __restrict__ p2w,
    short* __restrict__ p1wb, short* __restrict__ p2wb)
{
    int i = blockIdx.x * 256 + threadIdx.x;
    if (i < PP * LL) p1wb[i] = f2b(p1w[i]);
    else if (i < PP * LL + 2 * PP * PP) { int j = i - PP * LL; p2wb[j] = f2b(p2w[j]); }
}

// ---------------- gate features: 8-way partial sums over n ----------------
__global__ __launch_bounds__(384) void gmean_part(
    const float* __restrict__ T, float* __restrict__ G8)
{
    int b = blockIdx.x, c = blockIdx.y;
    int l = threadIdx.x;
    if (l >= LL) return;
    int n_lo = c * 41, n_hi = (NN < n_lo + 41) ? NN : (n_lo + 41);
    const float* tp = T + ((size_t)b * NN + n_lo) * LL + l;
    float s = 0.f;
    for (int n = n_lo; n < n_hi; ++n, tp += LL) s += *tp;
    G8[((size_t)c * BB + b) * LL + l] = s;
}

__global__ __launch_bounds__(384) void gmean_red(
    const float* __restrict__ G8, float* __restrict__ G)
{
    int b = blockIdx.x;
    int l = threadIdx.x;
    if (l >= LL) return;
    float s = 0.f;
    #pragma unroll
    for (int c = 0; c < 8; ++c) s += G8[((size_t)c * BB + b) * LL + l];
    G[b * LL + l] = s * (1.0f / NN);
}

// ---------------- noisy top-k gating + aux loss (512 thr, 4-way dot split) ----------------
__global__ __launch_bounds__(512) void gating_kernel(
    const float* __restrict__ G, const float* __restrict__ wg,
    const float* __restrict__ wn, const float* __restrict__ noise,
    int* __restrict__ IDX, float* __restrict__ GV, float* __restrict__ loss)
{
    __shared__ float pc[BB][EE][4], pn[BB][EE][4];
    __shared__ float s_clean[BB][EE], s_nstd[BB][EE], s_noisy[BB][EE], s_gates[BB][EE];
    __shared__ float s_thr_in[BB], s_thr_out[BB];
    __shared__ float s_imp[EE], s_load[EE];
    int tid = threadIdx.x;
    {
        int b = tid >> 4, e = (tid >> 2) & 3, sub = tid & 3;
        float c = 0.f, nr = 0.f;
        const float* gp = G + b * LL;
        for (int l = sub * 84; l < sub * 84 + 84; ++l) {
            float gv = gp[l];
            c  = fmaf(gv, wg[l * EE + e], c);
            nr = fmaf(gv, wn[l * EE + e], nr);
        }
        pc[b][e][sub] = c; pn[b][e][sub] = nr;
    }
    __syncthreads();
    int b = tid >> 2, e = tid & 3;   // valid for tid < 128
    if (tid < 128) {
        float c  = ((pc[b][e][0] + pc[b][e][1]) + pc[b][e][2]) + pc[b][e][3];
        float nr = ((pn[b][e][0] + pn[b][e][1]) + pn[b][e][2]) + pn[b][e][3];
        float nstd  = softplus_f(nr) + 1e-2f;
        float noisy = fmaf(noise[b * EE + e], nstd, c);
        s_clean[b][e] = c; s_nstd[b][e] = nstd; s_noisy[b][e] = noisy;
    }
    __syncthreads();
    if (tid < 128 && e == 0) {
        float v[4];
        #pragma unroll
        for (int i = 0; i < 4; ++i) v[i] = s_noisy[b][i];
        int i0 = 0;
        for (int i = 1; i < 4; ++i) if (v[i] > v[i0]) i0 = i;
        int i1 = -1;
        for (int i = 0; i < 4; ++i) { if (i == i0) continue; if (i1 < 0 || v[i] > v[i1]) i1 = i; }
        float m3 = -1e30f;
        for (int i = 0; i < 4; ++i) { if (i == i0 || i == i1) continue; if (v[i] > m3) m3 = v[i]; }
        float e1  = expf(v[i1] - v[i0]);
        float invd = 1.0f / (1.0f + e1);
        #pragma unroll
        for (int i = 0; i < 4; ++i) s_gates[b][i] = 0.f;
        s_gates[b][i0] = invd;
        s_gates[b][i1] = e1 * invd;
        s_thr_in[b]  = m3;       // (k+1)-th value
        s_thr_out[b] = v[i1];    // k-th value
        IDX[2*b] = i0; IDX[2*b+1] = i1;
        GV[2*b] = invd; GV[2*b+1] = e1 * invd;
    }
    __syncthreads();
    if (tid < EE) {
        int ee = tid;
        float imp = 0.f, ld = 0.f;
        for (int bb2 = 0; bb2 < BB; ++bb2) {
            imp += s_gates[bb2][ee];
            float thr = (s_noisy[bb2][ee] > s_thr_in[bb2]) ? s_thr_in[bb2] : s_thr_out[bb2];
            float z = (s_clean[bb2][ee] - thr) / s_nstd[bb2][ee];
            ld += 0.5f * (1.0f + erff(z * 0.7071067811865476f));
        }
        s_imp[ee] = imp; s_load[ee] = ld;
    }
    __syncthreads();
    if (tid == 0) {
        float aux = 0.f;
        {
            float m = (s_imp[0] + s_imp[1] + s_imp[2] + s_imp[3]) * 0.25f;
            float var = 0.f;
            for (int i = 0; i < 4; ++i) { float d = s_imp[i] - m; var += d * d; }
            var *= (1.0f / 3.0f);
            aux += var / (m * m + 1e-10f);
        }
        {
            float m = (s_load[0] + s_load[1] + s_load[2] + s_load[3]) * 0.25f;
            float var = 0.f;
            for (int i = 0; i < 4; ++i) { float d = s_load[i] - m; var += d * d; }
            var *= (1.0f / 3.0f);
            aux += var / (m * m + 1e-10f);
        }
        loss[0] += 0.01f * aux;
    }
}

// ---------------- FC1 (MFMA, zero-LDS/zero-barrier): Hs[z] = g*gelu(T@W1+b1) ----------------
// grid (4, 6, 64): x = d-tile(128), y = m-tile(64), z = b*2+slot. Direct-global fragments.
__global__ __launch_bounds__(256) void fc1_mfma(
    const short* __restrict__ Tb16, const short* __restrict__ W1t_l,
    const float* __restrict__ b1_l, const int* __restrict__ IDX,
    const float* __restrict__ GV, short* __restrict__ Hs)
{
    int z = blockIdx.z;
    int b = z >> 1;
    int e = IDX[z];
    float g = GV[z];
    int m0 = blockIdx.y * 64, n0 = blockIdx.x * 128;
    int tid = threadIdx.x;
    int wave = tid >> 6, lane = tid & 63, quad = lane >> 4, l16 = lane & 15;
    int wn = wave * 32;
    // per-lane fragment base pointers (16B-aligned)
    const short* Ab = Tb16 + ((size_t)b * NN + m0 + l16) * LP + quad * 8;
    const short* Bb = W1t_l + ((size_t)e * DHID + n0 + wn + l16) * LP + quad * 8;
    float4v zero4 = {0.f, 0.f, 0.f, 0.f};
    float4v acc[4][2];
    #pragma unroll
    for (int i = 0; i < 4; ++i)
        #pragma unroll
        for (int j = 0; j < 2; ++j) acc[i][j] = zero4;

    #pragma unroll
    for (int ks = 0; ks < 11; ++ks) {        // K = 352 (pad zeros beyond 336)
        int off = ks * 32;
        short8 af[4], bfv[2];
        #pragma unroll
        for (int mi = 0; mi < 4; ++mi) af[mi] = *(const short8*)(Ab + (size_t)mi * 16 * LP + off);
        #pragma unroll
        for (int ni = 0; ni < 2; ++ni) bfv[ni] = *(const short8*)(Bb + (size_t)ni * 16 * LP + off);
        #pragma unroll
        for (int mi = 0; mi < 4; ++mi)
            #pragma unroll
            for (int ni = 0; ni < 2; ++ni)
                acc[mi][ni] = __builtin_amdgcn_mfma_f32_16x16x32_bf16(af[mi], bfv[ni], acc[mi][ni], 0, 0, 0);
    }
    const float* bb = b1_l + (size_t)e * DHID;
    float bias[2];
    #pragma unroll
    for (int ni = 0; ni < 2; ++ni) bias[ni] = bb[n0 + wn + ni * 16 + l16];
    short* Ho = Hs + (size_t)z * NN * DHID;
    #pragma unroll
    for (int mi = 0; mi < 4; ++mi) {
        #pragma unroll
        for (int r = 0; r < 4; ++r) {
            int gm = m0 + mi * 16 + quad * 4 + r;   // C/D: col=lane&15, row=quad*4+reg
            if (gm >= NN) continue;
            #pragma unroll
            for (int ni = 0; ni < 2; ++ni) {
                int gd = n0 + wn + ni * 16 + l16;
                float v = acc[mi][ni][r] + bias[ni];
                Ho[(size_t)gm * DHID + gd] = f2b(g * gelu_f(v));
            }
        }
    }
}

// ---------------- FC2 (MFMA, zero-LDS/zero-barrier): T += sum_slot Hs@W2[e] + bias ----------------
// grid (3, 6, 32): x = l-tile(128), y = m-tile(64), z = b. K = 2 x 512 slot-switched.
__global__ __launch_bounds__(256) void fc2_mfma(
    const short* __restrict__ Hs, const short* __restrict__ W2t_l,
    const float* __restrict__ b2_l, float* __restrict__ T, short* __restrict__ Tb16,
    const int* __restrict__ IDX, const float* __restrict__ GV)
{
    int b = blockIdx.z;
    int m0 = blockIdx.y * 64, n0 = blockIdx.x * 128;
    int tid = threadIdx.x;
    int wave = tid >> 6, lane = tid & 63, quad = lane >> 4, l16 = lane & 15;
    int wn = wave * 32;
    float4v zero4 = {0.f, 0.f, 0.f, 0.f};
    float4v acc[4][2];
    #pragma unroll
    for (int i = 0; i < 4; ++i)
        #pragma unroll
        for (int j = 0; j < 2; ++j) acc[i][j] = zero4;

    #pragma unroll
    for (int slot = 0; slot < 2; ++slot) {
        int e = IDX[2 * b + slot];
        const short* Ab = Hs + ((size_t)(2 * b + slot) * NN + m0 + l16) * DHID + quad * 8;
        const short* Bb = W2t_l + ((size_t)e * LL + n0 + wn + l16) * DHID + quad * 8;
        #pragma unroll
        for (int ks = 0; ks < 16; ++ks) {
            int off = ks * 32;
            short8 af[4], bfv[2];
            #pragma unroll
            for (int mi = 0; mi < 4; ++mi) af[mi] = *(const short8*)(Ab + (size_t)mi * 16 * DHID + off);
            #pragma unroll
            for (int ni = 0; ni < 2; ++ni) bfv[ni] = *(const short8*)(Bb + (size_t)ni * 16 * DHID + off);
            #pragma unroll
            for (int mi = 0; mi < 4; ++mi)
                #pragma unroll
                for (int ni = 0; ni < 2; ++ni)
                    acc[mi][ni] = __builtin_amdgcn_mfma_f32_16x16x32_bf16(af[mi], bfv[ni], acc[mi][ni], 0, 0, 0);
        }
    }
    int e0 = IDX[2 * b], e1 = IDX[2 * b + 1];
    float g0 = GV[2 * b], g1 = GV[2 * b + 1];
    const float* b2e0 = b2_l + (size_t)e0 * LL;
    const float* b2e1 = b2_l + (size_t)e1 * LL;
    float bias[2]; int glc[2];
    #pragma unroll
    for (int ni = 0; ni < 2; ++ni) {
        int gl = n0 + wn + ni * 16 + l16;
        glc[ni] = gl;
        bias[ni] = (gl < LL) ? (g0 * b2e0[gl] + g1 * b2e1[gl]) : 0.f;
    }
    float* Tb = T + (size_t)b * NN * LL;
    short* Tb16b = Tb16 + (size_t)b * NN * LP;
    #pragma unroll
    for (int mi = 0; mi < 4; ++mi) {
        #pragma unroll
        for (int r = 0; r < 4; ++r) {
            int gm = m0 + mi * 16 + quad * 4 + r;
            if (gm >= NN) continue;
            #pragma unroll
            for (int ni = 0; ni < 2; ++ni) {
                if (glc[ni] < LL) {
                    size_t o = (size_t)gm * LL + glc[ni];
                    float vnew = Tb[o] + acc[mi][ni][r] + bias[ni];
                    Tb[o] = vnew;
                    Tb16b[(size_t)gm * LP + glc[ni]] = f2b(vnew);
                }
            }
        }
    }
}

// ---------------- fused projection head (MFMA), transposed phase 2 ----------------
__global__ __launch_bounds__(256) void proj_fused(
    const short* __restrict__ Tb16,
    const short* __restrict__ p1wb, const float* __restrict__ p1b,
    const short* __restrict__ p2wb, const float* __restrict__ p2b,
    float* __restrict__ out)
{
    __shared__ short smem[26624];                       // 52 KB, manually carved
    short (*Al)[40]   = (short (*)[40])smem;            // 64x40   (phase 1)
    short (*Bl1)[40]  = (short (*)[40])(smem + 2560);   // 96x40   (phase 1)
    short (*B2)[104]  = (short (*)[104])smem;           // 192x104 (phase 2, overlays Al/Bl1)
    short (*Hp)[104]  = (short (*)[104])(smem + 19968); // 64x104

    int m0 = blockIdx.x * 64;
    int tid = threadIdx.x;
    int wave = tid >> 6, lane = tid & 63, quad = lane >> 4, l16 = lane & 15;
    float4v zero4 = {0.f, 0.f, 0.f, 0.f};

    // ---- phase 1: 64 x 96 = T-tile @ p1w^T ----
    float4v acc1[6];
    #pragma unroll
    for (int i = 0; i < 6; ++i) acc1[i] = zero4;
    int am = tid >> 2, ako = (tid & 3) * 8;
    for (int k0 = 0; k0 < LL; k0 += 32) {
        {
            int gm = m0 + am;
            uint4 val = make_uint4(0, 0, 0, 0);
            if (gm < MROWS) val = *(const uint4*)(Tb16 + (size_t)gm * LP + k0 + ako);  // pad zeros
            *(uint4*)&Al[am][ako] = val;
        }
        #pragma unroll
        for (int uu = 0; uu < 2; ++uu) {
            int u = tid + uu * 256;
            if (u < 384) {
                int n = u >> 2, ko = (u & 3) * 8;
                int gk = k0 + ko;
                uint4 val = make_uint4(0, 0, 0, 0);
                if (gk < LL) val = *(const uint4*)(p1wb + (size_t)n * LL + gk);
                *(uint4*)&Bl1[n][ko] = val;
            }
        }
        __syncthreads();
        short8 af = *(const short8*)&Al[wave * 16 + l16][quad * 8];
        #pragma unroll
        for (int ni = 0; ni < 6; ++ni) {
            short8 bfv = *(const short8*)&Bl1[ni * 16 + l16][quad * 8];
            acc1[ni] = __builtin_amdgcn_mfma_f32_16x16x32_bf16(af, bfv, acc1[ni], 0, 0, 0);
        }
        __syncthreads();   // also protects Al/Bl1 before B2 overlay
    }
    // write Hp tile (LDS) + stage p2w fully into B2 (overlays Al/Bl1 — safe after sync)
    #pragma unroll
    for (int ni = 0; ni < 6; ++ni) {
        #pragma unroll
        for (int r = 0; r < 4; ++r) {
            int ml = wave * 16 + quad * 4 + r;
            int p = ni * 16 + l16;
            Hp[ml][p] = f2b(fast_tanh(acc1[ni][r] + p1b[p]));
        }
    }
    for (int u = tid; u < 192 * 12; u += 256) {
        int n = u / 12, ko = (u - n * 12) * 8;
        *(uint4*)&B2[n][ko] = *(const uint4*)(p2wb + (size_t)n * PP + ko);
    }
    __syncthreads();

    // ---- phase 2 (transposed): rows = c (192), cols = node (64), K = 96 ----
    float4v acc2[3][4];
    #pragma unroll
    for (int i = 0; i < 3; ++i)
        #pragma unroll
        for (int j = 0; j < 4; ++j) acc2[i][j] = zero4;
    #pragma unroll
    for (int kc = 0; kc < 3; ++kc) {
        int k0 = kc * 32 + quad * 8;
        short8 af[3], bfv[4];
        #pragma unroll
        for (int mi = 0; mi < 3; ++mi) af[mi] = *(const short8*)&B2[wave * 48 + mi * 16 + l16][k0];
        #pragma unroll
        for (int ni = 0; ni < 4; ++ni) bfv[ni] = *(const short8*)&Hp[ni * 16 + l16][k0];
        #pragma unroll
        for (int mi = 0; mi < 3; ++mi)
            #pragma unroll
            for (int ni = 0; ni < 4; ++ni)
                acc2[mi][ni] = __builtin_amdgcn_mfma_f32_16x16x32_bf16(af[mi], bfv[ni], acc2[mi][ni], 0, 0, 0);
    }
    // stores: lane l16 -> consecutive node (coalesced 64B runs per quad)
    int bqv[4], ndv[4]; bool okv[4];
    #pragma unroll
    for (int ni = 0; ni < 4; ++ni) {
        int gm = m0 + ni * 16 + l16;
        okv[ni] = (gm < MROWS);
        int bq = gm / NN;
        bqv[ni] = bq; ndv[ni] = gm - bq * NN;
    }
    #pragma unroll
    for (int mi = 0; mi < 3; ++mi) {
        #pragma unroll
        for (int r = 0; r < 4; ++r) {
            int c = wave * 48 + mi * 16 + quad * 4 + r;
            float pb = p2b[c];
            int p = c >> 1;
            if ((r & 1) == 0) {               // c even -> mean
                #pragma unroll
                for (int ni = 0; ni < 4; ++ni) {
                    if (!okv[ni]) continue;
                    float v = acc2[mi][ni][r] + pb;
                    out[((size_t)bqv[ni] * PP + p) * NN + ndv[ni]] = v;
                }
            } else {                          // c odd -> std
                #pragma unroll
                for (int ni = 0; ni < 4; ++ni) {
                    if (!okv[ni]) continue;
                    float v = acc2[mi][ni][r] + pb;
                    out[BPN + 1 + ((size_t)bqv[ni] * PP + p) * NN + ndv[ni]] = softplus_f(v) + 1e-6f;
                }
            }
        }
    }
}

__global__ void loss_write_kernel(const float* __restrict__ loss, float* __restrict__ out)
{
    if (threadIdx.x == 0) out[BPN] = loss[0];
}

extern "C" void kernel_launch(void* const* d_in, const int* in_sizes, int n_in,
                              void* d_out, int out_size, void* d_ws, size_t ws_size,
                              hipStream_t stream)
{
    const float* x     = (const float*)d_in[0];
    const float* noise = (const float*)d_in[1];
    const float* wg    = (const float*)d_in[2];
    const float* wn    = (const float*)d_in[3];
    const float* W1    = (const float*)d_in[4];
    const float* b1    = (const float*)d_in[5];
    const float* W2    = (const float*)d_in[6];
    const float* b2    = (const float*)d_in[7];
    const float* p1w   = (const float*)d_in[8];
    const float* p1b   = (const float*)d_in[9];
    const float* p2w   = (const float*)d_in[10];
    const float* p2b   = (const float*)d_in[11];
    float* out = (float*)d_out;

    float* ws   = (float*)d_ws;
    float* T    = ws;                          // STOT fp32 (stride LL)
    float* G8   = T + STOT;                    // 8*BB*LL
    float* G    = G8 + 8 * BB * LL;            // BB*LL
    float* LOSS = G + BB * LL;                 // 8
    float* GV   = LOSS + 8;                    // 64
    int*   IDX  = (int*)(GV + 64);             // 64
    float* MU   = (float*)(IDX + 64);          // BB*NN
    float* IV   = MU + MROWS;                  // BB*NN
    short* W1t  = (short*)(IV + MROWS);        // NLAYERS*EE*DHID*LP bf16 [le][d][k]
    short* W2t  = W1t + (size_t)NLAYERS * EE * DHID * LP;  // NLAYERS*EE*LL*DHID
    short* p1wb = W2t + (size_t)NLAYERS * EE * LL * DHID;  // 96*336
    short* p2wb = p1wb + PP * LL;              // 192*96
    short* Tb16 = p2wb + 2 * PP * PP;          // MROWS x LP bf16 mirror of T
    short* Hs   = Tb16 + (size_t)MROWS * LP;   // (64*NN + 128 slack) x DHID bf16

    revin_stats<<<dim3(BB, 6), 256, 0, stream>>>(x, MU, IV, LOSS);
    revin_tn<<<dim3(BB, 6, 7), 256, 0, stream>>>(x, MU, IV, T, Tb16);

    pcvt_kernel<<<(PP * LL + 2 * PP * PP + 255) / 256, 256, 0, stream>>>(p1w, p2w, p1wb, p2wb);
    // all-layer weight transposes up front (overlap with layer-0 compute)
    wtrans_kernel<<<dim3(8, 6, NLAYERS * EE), 256, 0, stream>>>(W1, W1t, LL, DHID, LP);
    wtrans_kernel<<<dim3(6, 8, NLAYERS * EE), 256, 0, stream>>>(W2, W2t, DHID, LL, DHID);

    for (int l = 0; l < NLAYERS; ++l) {
        gmean_part<<<dim3(BB, 8), 384, 0, stream>>>(T, G8);
        gmean_red<<<BB, 384, 0, stream>>>(G8, G);
        gating_kernel<<<1, 512, 0, stream>>>(G, wg + (size_t)l * LL * EE, wn + (size_t)l * LL * EE,
                                             noise + (size_t)l * BB * EE, IDX, GV, LOSS);
        fc1_mfma<<<dim3(4, 6, 64), 256, 0, stream>>>(
            Tb16, W1t + (size_t)l * EE * DHID * LP, b1 + (size_t)l * EE * DHID, IDX, GV, Hs);
        fc2_mfma<<<dim3(3, 6, 32), 256, 0, stream>>>(
            Hs, W2t + (size_t)l * EE * LL * DHID, b2 + (size_t)l * EE * LL, T, Tb16, IDX, GV);
    }
    proj_fused<<<161, 256, 0, stream>>>(Tb16, p1wb, p1b, p2wb, p2b, out);
    loss_write_kernel<<<1, 64, 0, stream>>>(LOSS, out);
}

// Round 8
// 463.518 us; speedup vs baseline: 1.2899x; 1.2899x over previous
//
#include <hip/hip_runtime.h>
#include <hip/hip_bf16.h>

#define NLAYERS 3
#define BB 32
#define LL 336
#define LP 352                 // K-padded stride for Tb16 / W1t (zeros in pad)
#define NN 321
#define EE 4
#define DHID 512
#define PP 96
#define STOT (BB*NN*LL)        // 3451392
#define MROWS (BB*NN)          // 10272
#define BPN ((size_t)BB*PP*NN) // 986112

typedef __attribute__((ext_vector_type(8))) short short8;
typedef __attribute__((ext_vector_type(4))) float float4v;

union BF { __hip_bfloat16 h; short s; };

__device__ __forceinline__ short f2b(float f) { BF u; u.h = __float2bfloat16(f); return u.s; }

__device__ __forceinline__ float fast_tanh(float y) {
    float e = __expf(2.0f * y);
    return 1.0f - 2.0f / (e + 1.0f);   // exact limits at +-inf
}
__device__ __forceinline__ float gelu_f(float x) {
    return 0.5f * x * (1.0f + fast_tanh(0.7978845608028654f * (x + 0.044715f * x * x * x)));
}
__device__ __forceinline__ float softplus_f(float x) {
    return fmaxf(x, 0.0f) + log1pf(expf(-fabsf(x)));
}

// ---------------- RevIN stats: mu/inv per (b,n); also zeros loss ----------------
__global__ __launch_bounds__(256) void revin_stats(
    const float* __restrict__ x, float* __restrict__ MU, float* __restrict__ IV,
    float* __restrict__ loss)
{
    int b = blockIdx.x, nt = blockIdx.y;
    int tid = threadIdx.x;
    if (b == 0 && nt == 0 && tid == 0) loss[0] = 0.0f;
    int ni = tid & 63, lc = tid >> 6;
    int n = nt * 64 + ni;
    float s = 0.f, ss = 0.f;
    if (n < NN) {
        const float* xp = x + ((size_t)b * LL + lc * 84) * NN + n;
        for (int l = 0; l < 84; ++l, xp += NN) {
            float v = *xp; s += v; ss = fmaf(v, v, ss);
        }
    }
    __shared__ float Ss[4][64], Sq[4][64];
    Ss[lc][ni] = s; Sq[lc][ni] = ss;
    __syncthreads();
    if (lc == 0 && n < NN) {
        float st = ((Ss[0][ni] + Ss[1][ni]) + Ss[2][ni]) + Ss[3][ni];
        float sq = ((Sq[0][ni] + Sq[1][ni]) + Sq[2][ni]) + Sq[3][ni];
        float mu  = st * (1.0f / LL);
        float var = sq * (1.0f / LL) - mu * mu;   // ddof=0
        float inv = 1.0f / sqrtf(var + 1e-5f);
        MU[b * NN + n] = mu;
        IV[b * NN + n] = inv;
    }
}

// ---------------- RevIN transpose+normalize: T (stride LL) + Tb16 (stride LP) ----------------
__global__ __launch_bounds__(256) void revin_tn(
    const float* __restrict__ x, const float* __restrict__ MU, const float* __restrict__ IV,
    float* __restrict__ T, short* __restrict__ Tb16)
{
    int b = blockIdx.x, nt = blockIdx.y, lt = blockIdx.z;
    int n0 = nt * 64, l0 = lt * 48;
    __shared__ float Ls[48][65];
    int tid = threadIdx.x;
    #pragma unroll
    for (int i = 0; i < 12; ++i) {
        int lin = tid + i * 256;
        int li = lin >> 6, ni = lin & 63;
        int n = n0 + ni;
        Ls[li][ni] = (n < NN) ? x[((size_t)b * LL + l0 + li) * NN + n] : 0.f;
    }
    __syncthreads();
    int r = tid >> 2, q = tid & 3;
    int n = n0 + r;
    if (n >= NN) return;
    float mu = MU[b * NN + n], iv = IV[b * NN + n];
    size_t rowf = (size_t)(b * NN + n) * LL + l0;
    size_t rowb = (size_t)(b * NN + n) * LP + l0;
    #pragma unroll
    for (int k = 0; k < 3; ++k) {
        int c = (q + 4 * k) * 4;
        float4 v;
        v.x = (Ls[c    ][r] - mu) * iv;
        v.y = (Ls[c + 1][r] - mu) * iv;
        v.z = (Ls[c + 2][r] - mu) * iv;
        v.w = (Ls[c + 3][r] - mu) * iv;
        *(float4*)&T[rowf + c] = v;
        union { short s[4]; uint2 u; } pk;
        pk.s[0] = f2b(v.x); pk.s[1] = f2b(v.y); pk.s[2] = f2b(v.z); pk.s[3] = f2b(v.w);
        *(uint2*)&Tb16[rowb + c] = pk.u;
    }
    if (lt == 6 && q == 3) {   // zero the K-pad cols 336..352 (re-poisoned every call)
        size_t base = (size_t)(b * NN + n) * LP;
        *(uint4*)&Tb16[base + 336] = make_uint4(0, 0, 0, 0);
        *(uint4*)&Tb16[base + 344] = make_uint4(0, 0, 0, 0);
    }
}

// ---------------- tiled transpose+convert: dst[d][k(KS-strided)] <- bf16(src[k][d]) ----------------
__global__ __launch_bounds__(256) void wtrans_kernel(
    const float* __restrict__ src0, short* __restrict__ dst0, int K, int D, int KS)
{
    int le = blockIdx.z;
    const float* src = src0 + (size_t)le * K * D;
    short* dst = dst0 + (size_t)le * D * KS;
    int d0 = blockIdx.x * 64, k0 = blockIdx.y * 64;
    __shared__ short Ws[64][72];
    int tid = threadIdx.x;
    #pragma unroll
    for (int i = 0; i < 16; ++i) {
        int lin = tid + i * 256;
        int ki = lin >> 6, dj = lin & 63;
        int k = k0 + ki, d = d0 + dj;
        Ws[ki][dj] = (k < K && d < D) ? f2b(src[(size_t)k * D + d]) : (short)0;
    }
    __syncthreads();
    int di = tid >> 2, d = d0 + di;
    if (d >= D) return;
    #pragma unroll
    for (int kp = 0; kp < 2; ++kp) {
        int kj = ((tid & 3) + 4 * kp) * 8;
        if (k0 + kj >= KS) continue;
        union { short s[8]; uint4 u; } pk;
        #pragma unroll
        for (int j = 0; j < 8; ++j) pk.s[j] = Ws[kj + j][di];
        *(uint4*)(dst + (size_t)d * KS + k0 + kj) = pk.u;
    }
}

// ---------------- small convert for p1w/p2w (already [n][k]) ----------------
__global__ __launch_bounds__(256) void pcvt_kernel(
    const float* __restrict__ p1w, const float* __restrict__ p2w,
    short* __restrict__ p1wb, short* __restrict__ p2wb)
{
    int i = blockIdx.x * 256 + threadIdx.x;
    if (i < PP * LL) p1wb[i] = f2b(p1w[i]);
    else if (i < PP * LL + 2 * PP * PP) { int j = i - PP * LL; p2wb[j] = f2b(p2w[j]); }
}

// ---------------- gate features: 8-way partial sums over n ----------------
__global__ __launch_bounds__(384) void gmean_part(
    const float* __restrict__ T, float* __restrict__ G8)
{
    int b = blockIdx.x, c = blockIdx.y;
    int l = threadIdx.x;
    if (l >= LL) return;
    int n_lo = c * 41, n_hi = (NN < n_lo + 41) ? NN : (n_lo + 41);
    const float* tp = T + ((size_t)b * NN + n_lo) * LL + l;
    float s = 0.f;
    for (int n = n_lo; n < n_hi; ++n, tp += LL) s += *tp;
    G8[((size_t)c * BB + b) * LL + l] = s;
}

__global__ __launch_bounds__(384) void gmean_red(
    const float* __restrict__ G8, float* __restrict__ G)
{
    int b = blockIdx.x;
    int l = threadIdx.x;
    if (l >= LL) return;
    float s = 0.f;
    #pragma unroll
    for (int c = 0; c < 8; ++c) s += G8[((size_t)c * BB + b) * LL + l];
    G[b * LL + l] = s * (1.0f / NN);
}

// ---------------- noisy top-k gating + aux loss (512 thr, 4-way dot split) ----------------
__global__ __launch_bounds__(512) void gating_kernel(
    const float* __restrict__ G, const float* __restrict__ wg,
    const float* __restrict__ wn, const float* __restrict__ noise,
    int* __restrict__ IDX, float* __restrict__ GV, float* __restrict__ loss)
{
    __shared__ float pc[BB][EE][4], pn[BB][EE][4];
    __shared__ float s_clean[BB][EE], s_nstd[BB][EE], s_noisy[BB][EE], s_gates[BB][EE];
    __shared__ float s_thr_in[BB], s_thr_out[BB];
    __shared__ float s_imp[EE], s_load[EE];
    int tid = threadIdx.x;
    {
        int b = tid >> 4, e = (tid >> 2) & 3, sub = tid & 3;
        float c = 0.f, nr = 0.f;
        const float* gp = G + b * LL;
        for (int l = sub * 84; l < sub * 84 + 84; ++l) {
            float gv = gp[l];
            c  = fmaf(gv, wg[l * EE + e], c);
            nr = fmaf(gv, wn[l * EE + e], nr);
        }
        pc[b][e][sub] = c; pn[b][e][sub] = nr;
    }
    __syncthreads();
    int b = tid >> 2, e = tid & 3;   // valid for tid < 128
    if (tid < 128) {
        float c  = ((pc[b][e][0] + pc[b][e][1]) + pc[b][e][2]) + pc[b][e][3];
        float nr = ((pn[b][e][0] + pn[b][e][1]) + pn[b][e][2]) + pn[b][e][3];
        float nstd  = softplus_f(nr) + 1e-2f;
        float noisy = fmaf(noise[b * EE + e], nstd, c);
        s_clean[b][e] = c; s_nstd[b][e] = nstd; s_noisy[b][e] = noisy;
    }
    __syncthreads();
    if (tid < 128 && e == 0) {
        float v[4];
        #pragma unroll
        for (int i = 0; i < 4; ++i) v[i] = s_noisy[b][i];
        int i0 = 0;
        for (int i = 1; i < 4; ++i) if (v[i] > v[i0]) i0 = i;
        int i1 = -1;
        for (int i = 0; i < 4; ++i) { if (i == i0) continue; if (i1 < 0 || v[i] > v[i1]) i1 = i; }
        float m3 = -1e30f;
        for (int i = 0; i < 4; ++i) { if (i == i0 || i == i1) continue; if (v[i] > m3) m3 = v[i]; }
        float e1  = expf(v[i1] - v[i0]);
        float invd = 1.0f / (1.0f + e1);
        #pragma unroll
        for (int i = 0; i < 4; ++i) s_gates[b][i] = 0.f;
        s_gates[b][i0] = invd;
        s_gates[b][i1] = e1 * invd;
        s_thr_in[b]  = m3;       // (k+1)-th value
        s_thr_out[b] = v[i1];    // k-th value
        IDX[2*b] = i0; IDX[2*b+1] = i1;
        GV[2*b] = invd; GV[2*b+1] = e1 * invd;
    }
    __syncthreads();
    if (tid < EE) {
        int ee = tid;
        float imp = 0.f, ld = 0.f;
        for (int bb2 = 0; bb2 < BB; ++bb2) {
            imp += s_gates[bb2][ee];
            float thr = (s_noisy[bb2][ee] > s_thr_in[bb2]) ? s_thr_in[bb2] : s_thr_out[bb2];
            float z = (s_clean[bb2][ee] - thr) / s_nstd[bb2][ee];
            ld += 0.5f * (1.0f + erff(z * 0.7071067811865476f));
        }
        s_imp[ee] = imp; s_load[ee] = ld;
    }
    __syncthreads();
    if (tid == 0) {
        float aux = 0.f;
        {
            float m = (s_imp[0] + s_imp[1] + s_imp[2] + s_imp[3]) * 0.25f;
            float var = 0.f;
            for (int i = 0; i < 4; ++i) { float d = s_imp[i] - m; var += d * d; }
            var *= (1.0f / 3.0f);
            aux += var / (m * m + 1e-10f);
        }
        {
            float m = (s_load[0] + s_load[1] + s_load[2] + s_load[3]) * 0.25f;
            float var = 0.f;
            for (int i = 0; i < 4; ++i) { float d = s_load[i] - m; var += d * d; }
            var *= (1.0f / 3.0f);
            aux += var / (m * m + 1e-10f);
        }
        loss[0] += 0.01f * aux;
    }
}

// ---------------- FC1 (MFMA): A in LDS (full K, 1 barrier), B direct-global ----------------
// grid (4, 6, 64): x = d-tile(128), y = m-tile(64), z = b*2+slot
__global__ __launch_bounds__(256, 3) void fc1_mfma(
    const short* __restrict__ Tb16, const short* __restrict__ W1t_l,
    const float* __restrict__ b1_l, const int* __restrict__ IDX,
    const float* __restrict__ GV, short* __restrict__ Hs)
{
    int z = blockIdx.z;
    int b = z >> 1;
    int e = IDX[z];
    float g = GV[z];
    int m0 = blockIdx.y * 64, n0 = blockIdx.x * 128;
    int tid = threadIdx.x;
    int wave = tid >> 6, lane = tid & 63, quad = lane >> 4, l16 = lane & 15;
    int wn = wave * 32;
    __shared__ short Al[64][360];   // stride 360 shorts = 720B ≡ 20 banks → 2-way max
    {   // stage full 64 x 352 A tile once (over-tile rows read finite garbage, discarded)
        int r = tid >> 2, c0 = (tid & 3) * 8;
        const short* src = Tb16 + ((size_t)b * NN + m0 + r) * LP + c0;
        #pragma unroll
        for (int ks = 0; ks < 11; ++ks)
            *(uint4*)&Al[r][c0 + ks * 32] = *(const uint4*)(src + ks * 32);
    }
    __syncthreads();

    const short* Bb = W1t_l + ((size_t)e * DHID + n0 + wn + l16) * LP + quad * 8;
    float4v zero4 = {0.f, 0.f, 0.f, 0.f};
    float4v acc[4][2];
    #pragma unroll
    for (int i = 0; i < 4; ++i)
        #pragma unroll
        for (int j = 0; j < 2; ++j) acc[i][j] = zero4;

    #pragma unroll
    for (int ks = 0; ks < 11; ++ks) {   // barrier-free: B loads pipeline freely
        int off = ks * 32;
        short8 bf0 = *(const short8*)(Bb + off);
        short8 bf1 = *(const short8*)(Bb + (size_t)16 * LP + off);
        short8 af[4];
        #pragma unroll
        for (int mi = 0; mi < 4; ++mi) af[mi] = *(const short8*)&Al[mi * 16 + l16][off + quad * 8];
        #pragma unroll
        for (int mi = 0; mi < 4; ++mi) {
            acc[mi][0] = __builtin_amdgcn_mfma_f32_16x16x32_bf16(af[mi], bf0, acc[mi][0], 0, 0, 0);
            acc[mi][1] = __builtin_amdgcn_mfma_f32_16x16x32_bf16(af[mi], bf1, acc[mi][1], 0, 0, 0);
        }
    }
    const float* bb = b1_l + (size_t)e * DHID;
    float bias[2];
    #pragma unroll
    for (int ni = 0; ni < 2; ++ni) bias[ni] = bb[n0 + wn + ni * 16 + l16];
    short* Ho = Hs + (size_t)z * NN * DHID;
    #pragma unroll
    for (int mi = 0; mi < 4; ++mi) {
        #pragma unroll
        for (int r = 0; r < 4; ++r) {
            int gm = m0 + mi * 16 + quad * 4 + r;   // C/D: col=lane&15, row=quad*4+reg
            if (gm >= NN) continue;
            #pragma unroll
            for (int ni = 0; ni < 2; ++ni) {
                int gd = n0 + wn + ni * 16 + l16;
                float v = acc[mi][ni][r] + bias[ni];
                Ho[(size_t)gm * DHID + gd] = f2b(g * gelu_f(v));
            }
        }
    }
}

// ---------------- FC2 (MFMA): A LDS-chunked (K=256, 8 barriers), B direct-global ----------------
// grid (3, 6, 32): x = l-tile(128), y = m-tile(64), z = b. K = 2 x 512 slot-switched.
__global__ __launch_bounds__(256, 3) void fc2_mfma(
    const short* __restrict__ Hs, const short* __restrict__ W2t_l,
    const float* __restrict__ b2_l, float* __restrict__ T, short* __restrict__ Tb16,
    const int* __restrict__ IDX, const float* __restrict__ GV)
{
    int b = blockIdx.z;
    int m0 = blockIdx.y * 64, n0 = blockIdx.x * 128;
    int tid = threadIdx.x;
    int wave = tid >> 6, lane = tid & 63, quad = lane >> 4, l16 = lane & 15;
    int wn = wave * 32;
    __shared__ short Al[64][264];   // stride 264 shorts = 528B ≡ 4 banks → 2-way frag reads
    float4v zero4 = {0.f, 0.f, 0.f, 0.f};
    float4v acc[4][2];
    #pragma unroll
    for (int i = 0; i < 4; ++i)
        #pragma unroll
        for (int j = 0; j < 2; ++j) acc[i][j] = zero4;

    int r8 = tid >> 5, c0s = (tid & 31) * 8;
    #pragma unroll
    for (int chunk = 0; chunk < 4; ++chunk) {   // slot0 k0/k1, slot1 k0/k1 (same order as R6)
        int slot = chunk >> 1;
        int koff = (chunk & 1) * 256;
        int e = IDX[2 * b + slot];
        const short* As = Hs + ((size_t)(2 * b + slot) * NN + m0) * DHID + koff;
        #pragma unroll
        for (int i = 0; i < 8; ++i)
            *(uint4*)&Al[i * 8 + r8][c0s] = *(const uint4*)(As + (size_t)(i * 8 + r8) * DHID + c0s);
        __syncthreads();
        const short* Bb = W2t_l + ((size_t)e * LL + n0 + wn + l16) * DHID + koff + quad * 8;
        #pragma unroll
        for (int ks = 0; ks < 8; ++ks) {
            int off = ks * 32;
            short8 bf0 = *(const short8*)(Bb + off);
            short8 bf1 = *(const short8*)(Bb + (size_t)16 * DHID + off);
            short8 af[4];
            #pragma unroll
            for (int mi = 0; mi < 4; ++mi) af[mi] = *(const short8*)&Al[mi * 16 + l16][off + quad * 8];
            #pragma unroll
            for (int mi = 0; mi < 4; ++mi) {
                acc[mi][0] = __builtin_amdgcn_mfma_f32_16x16x32_bf16(af[mi], bf0, acc[mi][0], 0, 0, 0);
                acc[mi][1] = __builtin_amdgcn_mfma_f32_16x16x32_bf16(af[mi], bf1, acc[mi][1], 0, 0, 0);
            }
        }
        __syncthreads();
    }
    int e0 = IDX[2 * b], e1 = IDX[2 * b + 1];
    float g0 = GV[2 * b], g1 = GV[2 * b + 1];
    const float* b2e0 = b2_l + (size_t)e0 * LL;
    const float* b2e1 = b2_l + (size_t)e1 * LL;
    float bias[2]; int glc[2];
    #pragma unroll
    for (int ni = 0; ni < 2; ++ni) {
        int gl = n0 + wn + ni * 16 + l16;
        glc[ni] = gl;
        bias[ni] = (gl < LL) ? (g0 * b2e0[gl] + g1 * b2e1[gl]) : 0.f;
    }
    float* Tb = T + (size_t)b * NN * LL;
    short* Tb16b = Tb16 + (size_t)b * NN * LP;
    #pragma unroll
    for (int mi = 0; mi < 4; ++mi) {
        #pragma unroll
        for (int r = 0; r < 4; ++r) {
            int gm = m0 + mi * 16 + quad * 4 + r;
            if (gm >= NN) continue;
            #pragma unroll
            for (int ni = 0; ni < 2; ++ni) {
                if (glc[ni] < LL) {
                    size_t o = (size_t)gm * LL + glc[ni];
                    float vnew = Tb[o] + acc[mi][ni][r] + bias[ni];
                    Tb[o] = vnew;
                    Tb16b[(size_t)gm * LP + glc[ni]] = f2b(vnew);
                }
            }
        }
    }
}

// ---------------- fused projection head (MFMA), transposed phase 2 ----------------
__global__ __launch_bounds__(256) void proj_fused(
    const short* __restrict__ Tb16,
    const short* __restrict__ p1wb, const float* __restrict__ p1b,
    const short* __restrict__ p2wb, const float* __restrict__ p2b,
    float* __restrict__ out)
{
    __shared__ short smem[26624];                       // 52 KB, manually carved
    short (*Al)[40]   = (short (*)[40])smem;            // 64x40   (phase 1)
    short (*Bl1)[40]  = (short (*)[40])(smem + 2560);   // 96x40   (phase 1)
    short (*B2)[104]  = (short (*)[104])smem;           // 192x104 (phase 2, overlays Al/Bl1)
    short (*Hp)[104]  = (short (*)[104])(smem + 19968); // 64x104

    int m0 = blockIdx.x * 64;
    int tid = threadIdx.x;
    int wave = tid >> 6, lane = tid & 63, quad = lane >> 4, l16 = lane & 15;
    float4v zero4 = {0.f, 0.f, 0.f, 0.f};

    // ---- phase 1: 64 x 96 = T-tile @ p1w^T ----
    float4v acc1[6];
    #pragma unroll
    for (int i = 0; i < 6; ++i) acc1[i] = zero4;
    int am = tid >> 2, ako = (tid & 3) * 8;
    for (int k0 = 0; k0 < LL; k0 += 32) {
        {
            int gm = m0 + am;
            uint4 val = make_uint4(0, 0, 0, 0);
            if (gm < MROWS) val = *(const uint4*)(Tb16 + (size_t)gm * LP + k0 + ako);  // pad zeros
            *(uint4*)&Al[am][ako] = val;
        }
        #pragma unroll
        for (int uu = 0; uu < 2; ++uu) {
            int u = tid + uu * 256;
            if (u < 384) {
                int n = u >> 2, ko = (u & 3) * 8;
                int gk = k0 + ko;
                uint4 val = make_uint4(0, 0, 0, 0);
                if (gk < LL) val = *(const uint4*)(p1wb + (size_t)n * LL + gk);
                *(uint4*)&Bl1[n][ko] = val;
            }
        }
        __syncthreads();
        short8 af = *(const short8*)&Al[wave * 16 + l16][quad * 8];
        #pragma unroll
        for (int ni = 0; ni < 6; ++ni) {
            short8 bfv = *(const short8*)&Bl1[ni * 16 + l16][quad * 8];
            acc1[ni] = __builtin_amdgcn_mfma_f32_16x16x32_bf16(af, bfv, acc1[ni], 0, 0, 0);
        }
        __syncthreads();   // also protects Al/Bl1 before B2 overlay
    }
    // write Hp tile (LDS) + stage p2w fully into B2 (overlays Al/Bl1 — safe after sync)
    #pragma unroll
    for (int ni = 0; ni < 6; ++ni) {
        #pragma unroll
        for (int r = 0; r < 4; ++r) {
            int ml = wave * 16 + quad * 4 + r;
            int p = ni * 16 + l16;
            Hp[ml][p] = f2b(fast_tanh(acc1[ni][r] + p1b[p]));
        }
    }
    for (int u = tid; u < 192 * 12; u += 256) {
        int n = u / 12, ko = (u - n * 12) * 8;
        *(uint4*)&B2[n][ko] = *(const uint4*)(p2wb + (size_t)n * PP + ko);
    }
    __syncthreads();

    // ---- phase 2 (transposed): rows = c (192), cols = node (64), K = 96 ----
    float4v acc2[3][4];
    #pragma unroll
    for (int i = 0; i < 3; ++i)
        #pragma unroll
        for (int j = 0; j < 4; ++j) acc2[i][j] = zero4;
    #pragma unroll
    for (int kc = 0; kc < 3; ++kc) {
        int k0 = kc * 32 + quad * 8;
        short8 af[3], bfv[4];
        #pragma unroll
        for (int mi = 0; mi < 3; ++mi) af[mi] = *(const short8*)&B2[wave * 48 + mi * 16 + l16][k0];
        #pragma unroll
        for (int ni = 0; ni < 4; ++ni) bfv[ni] = *(const short8*)&Hp[ni * 16 + l16][k0];
        #pragma unroll
        for (int mi = 0; mi < 3; ++mi)
            #pragma unroll
            for (int ni = 0; ni < 4; ++ni)
                acc2[mi][ni] = __builtin_amdgcn_mfma_f32_16x16x32_bf16(af[mi], bfv[ni], acc2[mi][ni], 0, 0, 0);
    }
    // stores: lane l16 -> consecutive node (coalesced 64B runs per quad)
    int bqv[4], ndv[4]; bool okv[4];
    #pragma unroll
    for (int ni = 0; ni < 4; ++ni) {
        int gm = m0 + ni * 16 + l16;
        okv[ni] = (gm < MROWS);
        int bq = gm / NN;
        bqv[ni] = bq; ndv[ni] = gm - bq * NN;
    }
    #pragma unroll
    for (int mi = 0; mi < 3; ++mi) {
        #pragma unroll
        for (int r = 0; r < 4; ++r) {
            int c = wave * 48 + mi * 16 + quad * 4 + r;
            float pb = p2b[c];
            int p = c >> 1;
            if ((r & 1) == 0) {               // c even -> mean
                #pragma unroll
                for (int ni = 0; ni < 4; ++ni) {
                    if (!okv[ni]) continue;
                    float v = acc2[mi][ni][r] + pb;
                    out[((size_t)bqv[ni] * PP + p) * NN + ndv[ni]] = v;
                }
            } else {                          // c odd -> std
                #pragma unroll
                for (int ni = 0; ni < 4; ++ni) {
                    if (!okv[ni]) continue;
                    float v = acc2[mi][ni][r] + pb;
                    out[BPN + 1 + ((size_t)bqv[ni] * PP + p) * NN + ndv[ni]] = softplus_f(v) + 1e-6f;
                }
            }
        }
    }
}

__global__ void loss_write_kernel(const float* __restrict__ loss, float* __restrict__ out)
{
    if (threadIdx.x == 0) out[BPN] = loss[0];
}

extern "C" void kernel_launch(void* const* d_in, const int* in_sizes, int n_in,
                              void* d_out, int out_size, void* d_ws, size_t ws_size,
                              hipStream_t stream)
{
    const float* x     = (const float*)d_in[0];
    const float* noise = (const float*)d_in[1];
    const float* wg    = (const float*)d_in[2];
    const float* wn    = (const float*)d_in[3];
    const float* W1    = (const float*)d_in[4];
    const float* b1    = (const float*)d_in[5];
    const float* W2    = (const float*)d_in[6];
    const float* b2    = (const float*)d_in[7];
    const float* p1w   = (const float*)d_in[8];
    const float* p1b   = (const float*)d_in[9];
    const float* p2w   = (const float*)d_in[10];
    const float* p2b   = (const float*)d_in[11];
    float* out = (float*)d_out;

    float* ws   = (float*)d_ws;
    float* T    = ws;                          // STOT fp32 (stride LL)
    float* G8   = T + STOT;                    // 8*BB*LL
    float* G    = G8 + 8 * BB * LL;            // BB*LL
    float* LOSS = G + BB * LL;                 // 8
    float* GV   = LOSS + 8;                    // 64
    int*   IDX  = (int*)(GV + 64);             // 64
    float* MU   = (float*)(IDX + 64);          // BB*NN
    float* IV   = MU + MROWS;                  // BB*NN
    short* W1t  = (short*)(IV + MROWS);        // NLAYERS*EE*DHID*LP bf16 [le][d][k]
    short* W2t  = W1t + (size_t)NLAYERS * EE * DHID * LP;  // NLAYERS*EE*LL*DHID
    short* p1wb = W2t + (size_t)NLAYERS * EE * LL * DHID;  // 96*336
    short* p2wb = p1wb + PP * LL;              // 192*96
    short* Tb16 = p2wb + 2 * PP * PP;          // MROWS x LP bf16 mirror of T
    short* Hs   = Tb16 + (size_t)MROWS * LP;   // 64*NN rows + slack x DHID bf16

    revin_stats<<<dim3(BB, 6), 256, 0, stream>>>(x, MU, IV, LOSS);
    revin_tn<<<dim3(BB, 6, 7), 256, 0, stream>>>(x, MU, IV, T, Tb16);

    pcvt_kernel<<<(PP * LL + 2 * PP * PP + 255) / 256, 256, 0, stream>>>(p1w, p2w, p1wb, p2wb);
    // all-layer weight transposes up front (overlap with layer-0 compute)
    wtrans_kernel<<<dim3(8, 6, NLAYERS * EE), 256, 0, stream>>>(W1, W1t, LL, DHID, LP);
    wtrans_kernel<<<dim3(6, 8, NLAYERS * EE), 256, 0, stream>>>(W2, W2t, DHID, LL, DHID);

    for (int l = 0; l < NLAYERS; ++l) {
        gmean_part<<<dim3(BB, 8), 384, 0, stream>>>(T, G8);
        gmean_red<<<BB, 384, 0, stream>>>(G8, G);
        gating_kernel<<<1, 512, 0, stream>>>(G, wg + (size_t)l * LL * EE, wn + (size_t)l * LL * EE,
                                             noise + (size_t)l * BB * EE, IDX, GV, LOSS);
        fc1_mfma<<<dim3(4, 6, 64), 256, 0, stream>>>(
            Tb16, W1t + (size_t)l * EE * DHID * LP, b1 + (size_t)l * EE * DHID, IDX, GV, Hs);
        fc2_mfma<<<dim3(3, 6, 32), 256, 0, stream>>>(
            Hs, W2t + (size_t)l * EE * LL * DHID, b2 + (size_t)l * EE * LL, T, Tb16, IDX, GV);
    }
    proj_fused<<<161, 256, 0, stream>>>(Tb16, p1wb, p1b, p2wb, p2b, out);
    loss_write_kernel<<<1, 64, 0, stream>>>(LOSS, out);
}